// Round 1
// baseline (620.305 us; speedup 1.0000x reference)
//
#include <hip/hip_runtime.h>

// Problem: x [3,5,32,64,32,32] binary float. Per 32x32 image: connected
// components (4-neighbor) on fg = (x != 0); counts over labels INCLUDING
// background label 0; take max count -> per-image int. Then per (c,b,bt):
// sum over 64 patches, integer-divide by 64, output float32 [3,5,32] = 480.

#define IMG_PIX 1024   // 32*32
#define N_IMGS 30720   // 3*5*32*64
#define N_OUT  480     // 3*5*32
#define PATCHES 64

__device__ __forceinline__ int find_root(volatile int* L, int i) {
    // Invariant: L[i] <= i and L[i] indexes a foreground pixel, so chains
    // strictly decrease and terminate even under concurrent monotone updates.
    for (;;) {
        int p = L[i];
        if (p == i) return i;
        i = p;
    }
}

__global__ __launch_bounds__(1024)
void ccl_maxcount_kernel(const float* __restrict__ x, int* __restrict__ maxc) {
    __shared__ int label[IMG_PIX];
    __shared__ int cnt[IMG_PIX];
    __shared__ unsigned char fgArr[IMG_PIX];
    __shared__ int s_changed;
    __shared__ int s_bg;
    __shared__ int s_max;

    const int tid = threadIdx.x;
    const size_t img = blockIdx.x;

    const float v = x[img * IMG_PIX + tid];
    const bool fg = (v != 0.0f);

    label[tid] = tid;
    cnt[tid] = 0;
    fgArr[tid] = fg ? 1 : 0;
    if (tid == 0) { s_bg = 0; s_max = 0; }
    __syncthreads();

    const int row = tid >> 5;
    const int col = tid & 31;

    // Union-find style min-label propagation with pointer jumping.
    for (;;) {
        if (tid == 0) s_changed = 0;
        __syncthreads();

        if (fg) {
            int root = find_root(label, tid);
            int m = root;
            if (row > 0  && fgArr[tid - 32]) m = min(m, find_root(label, tid - 32));
            if (row < 31 && fgArr[tid + 32]) m = min(m, find_root(label, tid + 32));
            if (col > 0  && fgArr[tid - 1])  m = min(m, find_root(label, tid - 1));
            if (col < 31 && fgArr[tid + 1])  m = min(m, find_root(label, tid + 1));
            if (m < root) {
                atomicMin(&label[root], m);
                s_changed = 1;
            }
        }
        __syncthreads();
        if (!s_changed) break;
        // Path compression (concurrent, monotone-safe).
        if (fg) label[tid] = find_root(label, tid);
        __syncthreads();
    }

    // Count pixels per root; background via ballot popcount.
    if (fg) {
        atomicAdd(&cnt[find_root(label, tid)], 1);
    }
    unsigned long long bgmask = __ballot(!fg);
    if ((tid & 63) == 0) atomicAdd(&s_bg, (int)__popcll(bgmask));
    __syncthreads();

    // Max-reduce counts across the block (wave shuffle + shared atomic).
    int mval = cnt[tid];
    #pragma unroll
    for (int off = 32; off > 0; off >>= 1)
        mval = max(mval, __shfl_down(mval, off));
    if ((tid & 63) == 0) atomicMax(&s_max, mval);
    __syncthreads();

    if (tid == 0) {
        maxc[img] = max(s_max, s_bg);
    }
}

__global__ __launch_bounds__(64)
void patch_reduce_kernel(const int* __restrict__ maxc, float* __restrict__ out) {
    const int o = blockIdx.x;      // 0..479
    int v = maxc[(size_t)o * PATCHES + threadIdx.x];
    #pragma unroll
    for (int off = 32; off > 0; off >>= 1)
        v += __shfl_down(v, off);
    if (threadIdx.x == 0) out[o] = (float)(v >> 6);  // integer division by 64
}

extern "C" void kernel_launch(void* const* d_in, const int* in_sizes, int n_in,
                              void* d_out, int out_size, void* d_ws, size_t ws_size,
                              hipStream_t stream) {
    const float* x = (const float*)d_in[0];
    float* out = (float*)d_out;
    int* maxc = (int*)d_ws;   // 30720 ints = 120 KiB scratch

    ccl_maxcount_kernel<<<N_IMGS, IMG_PIX, 0, stream>>>(x, maxc);
    patch_reduce_kernel<<<N_OUT, 64, 0, stream>>>(maxc, out);
}

// Round 2
// 558.322 us; speedup vs baseline: 1.1110x; 1.1110x over previous
//
#include <hip/hip_runtime.h>
#include <stdint.h>

// x [3,5,32,64,32,32] binary float -> per 32x32 image max(component size, bg count)
// -> sum over 64 patches >> 6 -> float [480].
//
// Pipeline:
//  A) bitmask_kernel: float -> 32 uint32 row masks per image (ballot, coalesced).
//  B) ccl_runs_kernel: one image per LANE. Run-based union-find in per-thread LDS.
//  C) patch_reduce_kernel: wave-sum 64 patches, >>6, store float.

#define N_IMGS 30720
#define N_OUT  480

// ---------------- Kernel A: float -> row bitmasks ----------------
__global__ __launch_bounds__(1024)
void bitmask_kernel(const float* __restrict__ x, uint32_t* __restrict__ bm) {
    const int tid = threadIdx.x;
    const size_t img = blockIdx.x;
    const float v = x[img * 1024 + tid];
    unsigned long long mask = __ballot(v != 0.0f);
    if ((tid & 63) == 0) {
        // wave w covers pixels 64w..64w+63 = rows 2w,2w+1; low word is row 2w.
        *(unsigned long long*)(&bm[img * 32 + (tid >> 5)]) = mask;
    }
}

// ---------------- Kernel B: run-based union-find CCL ----------------
// Per-thread LDS: parent/size int16[448] (root stores -size), prevlab int16[32].
// Stride 482 shorts = 964 B -> 241 words (odd) -> lane bases hit all 32 banks.
#define PARENT_CAP 448
#define PSTRIDE    482

__device__ __forceinline__ int ufind(short* P, int i) {
    int r = i;
    int p;
    while ((p = P[r]) >= 0) r = p;          // walk to root (negative = -size)
    while ((p = P[i]) >= 0) { P[i] = (short)r; i = p; }  // path compression
    return r;
}

__global__ __launch_bounds__(64)
void ccl_runs_kernel(const uint32_t* __restrict__ bm, int* __restrict__ maxc) {
    __shared__ short uf[64 * PSTRIDE];      // 61,696 B
    const int tid = threadIdx.x;
    const int img = blockIdx.x * 64 + tid;  // 480 blocks * 64 = 30720 exactly
    short* P = &uf[tid * PSTRIDE];          // [0..447] UF, [448..479] prevlab

    const uint32_t* b = bm + (size_t)img * 32;
    uint32_t m[32];
    #pragma unroll
    for (int i = 0; i < 8; ++i) {
        uint4 q = ((const uint4*)b)[i];
        m[4*i+0] = q.x; m[4*i+1] = q.y; m[4*i+2] = q.z; m[4*i+3] = q.w;
    }

    int fgtot = 0;
    #pragma unroll
    for (int r = 0; r < 32; ++r) fgtot += __popc(m[r]);

    int nid = 0;        // next run id
    int mx = 0;         // max component size so far
    uint32_t pm = 0;    // previous row's mask

    #pragma unroll
    for (int r = 0; r < 32; ++r) {
        uint32_t mr = m[r];
        uint32_t rem = mr;
        while (rem) {
            int s = __ffs(rem) - 1;                 // run start
            uint32_t t  = rem + (1u << s);          // carry clears the run
            uint32_t rm = (t ^ rem) & rem;          // this run's bits
            rem &= ~rm;
            int len = __popc(rm);
            int id = nid++;
            P[id] = (short)(-len);
            mx = max(mx, len);
            int cr = id;                             // current root

            uint32_t ov = rm & pm;                   // overlap with prev row
            while (ov) {
                int c = __ffs(ov) - 1;
                int lab = P[PARENT_CAP + c];         // prev-row label at col c
                int lr = ufind(P, lab);
                if (lr != cr) {
                    int sa = -P[cr], sb = -P[lr];
                    int ns = sa + sb;
                    if (sa >= sb) { P[lr] = (short)cr; P[cr] = (short)(-ns); }
                    else          { P[cr] = (short)lr; P[lr] = (short)(-ns); cr = lr; }
                    mx = max(mx, ns);
                }
                // clear the whole overlapped prev-run extent (upward from c):
                uint32_t hi  = pm & ~((1u << c) - 1);    // prev bits >= c (bit c set)
                uint32_t clr = hi ^ (hi + (1u << c));    // bits c..runEnd(+1)
                ov &= ~clr;
            }

            // record this run's label for the next row
            uint32_t wcols = rm;
            while (wcols) {
                int c = __ffs(wcols) - 1;
                wcols &= wcols - 1;
                P[PARENT_CAP + c] = (short)id;
            }
        }
        pm = mr;
    }

    int bg = 1024 - fgtot;
    maxc[img] = max(mx, bg);
}

// ---------------- Kernel C: per-(c,b,bt) patch reduction ----------------
__global__ __launch_bounds__(64)
void patch_reduce_kernel(const int* __restrict__ maxc, float* __restrict__ out) {
    const int o = blockIdx.x;   // 0..479
    int v = maxc[(size_t)o * 64 + threadIdx.x];
    #pragma unroll
    for (int off = 32; off > 0; off >>= 1)
        v += __shfl_down(v, off);
    if (threadIdx.x == 0) out[o] = (float)(v >> 6);  // integer division by 64
}

extern "C" void kernel_launch(void* const* d_in, const int* in_sizes, int n_in,
                              void* d_out, int out_size, void* d_ws, size_t ws_size,
                              hipStream_t stream) {
    const float* x = (const float*)d_in[0];
    float* out = (float*)d_out;

    uint32_t* bm = (uint32_t*)d_ws;                         // 30720*32*4 = 3,932,160 B
    int* maxc = (int*)((char*)d_ws + (size_t)N_IMGS * 32 * 4);  // + 122,880 B

    bitmask_kernel<<<N_IMGS, 1024, 0, stream>>>(x, bm);
    ccl_runs_kernel<<<N_IMGS / 64, 64, 0, stream>>>(bm, maxc);
    patch_reduce_kernel<<<N_OUT, 64, 0, stream>>>(maxc, out);
}

// Round 3
// 240.397 us; speedup vs baseline: 2.5803x; 2.3225x over previous
//
#include <hip/hip_runtime.h>
#include <stdint.h>

// x [3,5,32,64,32,32] binary float -> per 32x32 image max(component size, bg count)
// -> sum over 64 patches >> 6 -> float [480].
//
// One WAVE per image (30720 waves = full machine). Lane r<32 owns row mask r.
// Runs-graph union-find in per-wave LDS (512 entries), atomicMin hooking +
// pointer jumping, wave-lockstep (no barriers), convergence via __any.

#define N_IMGS 30720
#define N_OUT  480
#define IMGS_PER_BLOCK 4   // 4 waves x 64 = 256 threads

__device__ __forceinline__ int findL(volatile int* L, int i) {
    int p = L[i];
    while (p != i) { i = p; p = L[i]; }
    return i;
}

__global__ __launch_bounds__(256)
void ccl_wave_kernel(const float* __restrict__ x, int* __restrict__ maxc) {
    __shared__ int Lbuf[IMGS_PER_BLOCK * 512];
    __shared__ int SZbuf[IMGS_PER_BLOCK * 512];

    const int lane = threadIdx.x & 63;
    const int wv   = threadIdx.x >> 6;
    const size_t img = (size_t)blockIdx.x * IMGS_PER_BLOCK + wv;
    volatile int* L  = (volatile int*)(Lbuf + wv * 512);
    volatile int* SZ = (volatile int*)(SZbuf + wv * 512);

    // ---- coalesced load: lane covers pixels [lane*16, lane*16+16) ----
    const float4* xp = (const float4*)(x + img * 1024 + lane * 16);
    uint32_t hb = 0;
    #pragma unroll
    for (int i = 0; i < 4; ++i) {
        float4 q = xp[i];
        hb |= (uint32_t)(q.x != 0.0f) << (4*i + 0);
        hb |= (uint32_t)(q.y != 0.0f) << (4*i + 1);
        hb |= (uint32_t)(q.z != 0.0f) << (4*i + 2);
        hb |= (uint32_t)(q.w != 0.0f) << (4*i + 3);
    }
    int fgcnt = __popc(hb);
    #pragma unroll
    for (int off = 32; off; off >>= 1) fgcnt += __shfl_xor(fgcnt, off);

    // lane 2r holds cols 0..15 of row r, lane 2r+1 cols 16..31
    uint32_t lo = __shfl(hb, 2 * lane);
    uint32_t hi = __shfl(hb, 2 * lane + 1);
    uint32_t m  = (lane < 32) ? (lo | (hi << 16)) : 0u;

    // ---- run numbering: wave prefix scan of per-row run counts ----
    uint32_t runStarts = m & ~(m << 1);
    int nruns = __popc(runStarts);
    int scan = nruns;
    #pragma unroll
    for (int off = 1; off < 64; off <<= 1) {
        int u = __shfl_up(scan, off);
        if (lane >= off) scan += u;
    }
    const int base = scan - nruns;   // exclusive prefix
    const int R    = __shfl(scan, 63);

    for (int i = lane; i < R; i += 64) L[i] = i;

    // ---- edges: one per overlap segment with the previous row ----
    uint32_t mprev  = __shfl_up(m, 1);
    uint32_t rsPrev = __shfl_up(runStarts, 1);
    int      bPrev  = __shfl_up(base, 1);
    if (lane == 0 || lane >= 32) mprev = 0;
    uint32_t ov  = m & mprev;
    uint32_t ovs = ov & ~(ov << 1);   // one bit per overlap segment

    // ---- hooking + compression rounds (wave-lockstep, no barriers) ----
    bool more = true;
    while (more) {
        bool changed = false;
        uint32_t t = ovs;
        while (t) {
            int c = __ffs(t) - 1; t &= t - 1;
            uint32_t mc = (2u << c) - 1;              // bits 0..c
            int a = base  + __popc(runStarts & mc) - 1;
            int b = bPrev + __popc(rsPrev    & mc) - 1;
            int ra = findL(L, a);
            int rb = findL(L, b);
            if (ra != rb) {
                atomicMin((int*)&L[max(ra, rb)], min(ra, rb));
                changed = true;
            }
        }
        for (int i = lane; i < R; i += 64) L[i] = findL(L, i);
        more = __any(changed);
    }

    // ---- component sizes ----
    for (int i = lane; i < R; i += 64) SZ[i] = 0;
    uint32_t mm = m;
    int k = 0;
    while (mm) {
        int s = __ffs(mm) - 1;
        uint32_t t2 = mm + (1u << s);
        uint32_t rm = (t2 ^ mm) & mm;    // this run's bits
        mm &= ~rm;
        atomicAdd((int*)&SZ[L[base + k]], __popc(rm));
        ++k;
    }

    int mx = 0;
    for (int i = lane; i < R; i += 64) mx = max(mx, SZ[i]);
    #pragma unroll
    for (int off = 32; off; off >>= 1) mx = max(mx, __shfl_xor(mx, off));

    if (lane == 0) maxc[img] = max(mx, 1024 - fgcnt);
}

__global__ __launch_bounds__(64)
void patch_reduce_kernel(const int* __restrict__ maxc, float* __restrict__ out) {
    const int o = blockIdx.x;   // 0..479
    int v = maxc[(size_t)o * 64 + threadIdx.x];
    #pragma unroll
    for (int off = 32; off > 0; off >>= 1)
        v += __shfl_down(v, off);
    if (threadIdx.x == 0) out[o] = (float)(v >> 6);  // integer division by 64
}

extern "C" void kernel_launch(void* const* d_in, const int* in_sizes, int n_in,
                              void* d_out, int out_size, void* d_ws, size_t ws_size,
                              hipStream_t stream) {
    const float* x = (const float*)d_in[0];
    float* out = (float*)d_out;
    int* maxc = (int*)d_ws;   // 30720 ints

    ccl_wave_kernel<<<N_IMGS / IMGS_PER_BLOCK, 256, 0, stream>>>(x, maxc);
    patch_reduce_kernel<<<N_OUT, 64, 0, stream>>>(maxc, out);
}

// Round 4
// 204.614 us; speedup vs baseline: 3.0316x; 1.1749x over previous
//
#include <hip/hip_runtime.h>
#include <stdint.h>

// x [3,5,32,64,32,32] binary float -> per 32x32 image max(component size, bg count)
// -> sum over 64 patches >> 6 -> float [480].
//
// TWO images per wave: lanes 0-31 own image A's rows, lanes 32-63 image B's.
// Row-per-lane bitmasks; runs numbered by segmented 64-lane scan; SINGLE-PASS
// lock-free union-find (atomicCAS hooking, read-only finds) in per-image LDS
// (512 entries); one compression pass; sizes packed into root entries
// (L[r] = r | size<<9). Wave-lockstep => no barriers anywhere.

#define N_IMGS 30720
#define N_OUT  480
#define WAVES_PER_BLOCK 4
#define IMGS_PER_BLOCK (WAVES_PER_BLOCK * 2)   // 8

__device__ __forceinline__ int findL(volatile const int* L, int i) {
    int p = L[i];
    while (p != i) { i = p; p = L[i]; }
    return i;
}

__global__ __launch_bounds__(256)
void ccl_wave2_kernel(const uint32_t* __restrict__ x, int* __restrict__ maxc) {
    __shared__ int Lbuf[IMGS_PER_BLOCK * 512];   // 16 KiB

    const int lane = threadIdx.x & 63;
    const int wv   = threadIdx.x >> 6;
    const int half = lane >> 5;                  // 0: image A, 1: image B
    const int row  = lane & 31;
    const size_t img = (size_t)blockIdx.x * IMGS_PER_BLOCK + wv * 2 + half;
    int* L = Lbuf + (wv * 2 + half) * 512;

    // ---- row-per-lane load: 8 x uint4 = 32 pixels (1.0f bits != 0) ----
    const uint4* rp = (const uint4*)(x + img * 1024 + row * 32);
    uint32_t m = 0;
    #pragma unroll
    for (int i = 0; i < 8; ++i) {
        uint4 q = rp[i];
        m |= (uint32_t)(q.x != 0u) << (4 * i + 0);
        m |= (uint32_t)(q.y != 0u) << (4 * i + 1);
        m |= (uint32_t)(q.z != 0u) << (4 * i + 2);
        m |= (uint32_t)(q.w != 0u) << (4 * i + 3);
    }

    // foreground count per image (butterfly within half-wave: offs < 32)
    int fg = __popc(m);
    #pragma unroll
    for (int off = 1; off < 32; off <<= 1) fg += __shfl_xor(fg, off);

    // ---- run numbering: 64-lane inclusive scan, segmented at lane 32 ----
    uint32_t runStarts = m & ~(m << 1);
    int nruns = __popc(runStarts);
    int scan = nruns;
    #pragma unroll
    for (int off = 1; off < 64; off <<= 1) {
        int u = __shfl_up(scan, off);
        if (lane >= off) scan += u;
    }
    const int totalA   = __shfl(scan, 31);
    const int totalAll = __shfl(scan, 63);
    const int base = scan - nruns - (half ? totalA : 0);
    const int R    = half ? (totalAll - totalA) : totalA;   // runs in my image

    for (int i = row; i < R; i += 32) L[i] = i;

    // ---- edges: one per overlap segment with previous row ----
    uint32_t mprev  = __shfl_up(m, 1);
    uint32_t rsPrev = __shfl_up(runStarts, 1);
    int      bPrev  = __shfl_up(base, 1);
    if (row == 0) mprev = 0;                 // row 0 of each image
    uint32_t ov  = m & mprev;
    uint32_t ovs = ov & ~(ov << 1);

    while (ovs) {
        int c = __ffs(ovs) - 1; ovs &= ovs - 1;
        uint32_t mc = (2u << c) - 1;         // bits 0..c (c=31 -> all ones)
        int a = base  + __popc(runStarts & mc) - 1;
        int b = bPrev + __popc(rsPrev    & mc) - 1;
        // single-pass lock-free union (hook larger root to smaller via CAS)
        int ra = findL(L, a);
        int rb = findL(L, b);
        while (ra != rb) {
            int hi = ra > rb ? ra : rb;
            int lo = ra ^ rb ^ hi;
            int old = atomicCAS(&L[hi], hi, lo);
            if (old == hi) break;            // hooked
            ra = findL(L, old);              // root moved; chase and retry
            rb = lo;
        }
    }

    // ---- one compression pass (no unions in flight now; lockstep) ----
    for (int i = row; i < R; i += 32) L[i] = findL(L, i);

    // ---- sizes packed into roots: L[r] = r | (size << 9) ----
    // adds are multiples of 512, low 9 bits (root id < 512) never carry.
    uint32_t mm = m; int k = 0;
    while (mm) {
        int s = __ffs(mm) - 1;
        uint32_t t  = mm + (1u << s);
        uint32_t rm = (t ^ mm) & mm;         // this run's bits
        mm &= ~rm;
        int root = L[base + k] & 511;
        atomicAdd(&L[root], __popc(rm) << 9);
        ++k;
    }

    // ---- max component size, per image ----
    int mx = 0;
    for (int i = row; i < R; i += 32) {
        int v = L[i];
        if ((v & 511) == i) mx = max(mx, v >> 9);
    }
    #pragma unroll
    for (int off = 1; off < 32; off <<= 1) mx = max(mx, __shfl_xor(mx, off));

    if (row == 0) maxc[img] = max(mx, 1024 - fg);
}

__global__ __launch_bounds__(64)
void patch_reduce_kernel(const int* __restrict__ maxc, float* __restrict__ out) {
    const int o = blockIdx.x;   // 0..479
    int v = maxc[(size_t)o * 64 + threadIdx.x];
    #pragma unroll
    for (int off = 32; off > 0; off >>= 1)
        v += __shfl_down(v, off);
    if (threadIdx.x == 0) out[o] = (float)(v >> 6);  // integer division by 64
}

extern "C" void kernel_launch(void* const* d_in, const int* in_sizes, int n_in,
                              void* d_out, int out_size, void* d_ws, size_t ws_size,
                              hipStream_t stream) {
    const uint32_t* x = (const uint32_t*)d_in[0];   // float bits; !=0 test
    float* out = (float*)d_out;
    int* maxc = (int*)d_ws;   // 30720 ints

    ccl_wave2_kernel<<<N_IMGS / IMGS_PER_BLOCK, 256, 0, stream>>>(x, maxc);
    patch_reduce_kernel<<<N_OUT, 64, 0, stream>>>(maxc, out);
}

// Round 5
// 194.182 us; speedup vs baseline: 3.1945x; 1.0537x over previous
//
#include <hip/hip_runtime.h>
#include <stdint.h>

// x [3,5,32,64,32,32] binary float -> per 32x32 image max(component size, bg count)
// -> sum over 64 patches >> 6 -> float [480].
//
// TWO images per wave: lanes 0-31 own image A's rows, lanes 32-63 image B's.
// Row-per-lane bitmasks (input is exactly 0.0f/1.0f -> pixel = floatbits>>29);
// runs numbered by segmented 64-lane scan; single-pass lock-free union-find
// (atomicCAS hooking to min root, PATH-HALVING finds) in per-image LDS (512
// ints). No compression pass: count phase finds roots directly and
// accumulates sizes into root entries as (root | size<<9); finds mask &511.
// Wave-lockstep => no barriers.

#define N_IMGS 30720
#define N_OUT  480
#define WAVES_PER_BLOCK 4
#define IMGS_PER_BLOCK (WAVES_PER_BLOCK * 2)   // 8

// Find with path halving. Entries: child -> plain parent id (<512, strictly
// smaller than child); root r -> r | (size<<9) (size bits only in count phase).
// Halving stores plain ancestor ids into CHILD slots only; root slots are only
// modified by CAS (edge phase) or atomicAdd (count phase).
__device__ __forceinline__ int findH(int* L, int i) {
    for (;;) {
        int p = L[i] & 511;
        if (p == i) return i;
        int g = L[p] & 511;
        if (g == p) return p;
        L[i] = g;          // halving: shortcut to grandparent (monotone-safe)
        i = g;
    }
}

__global__ __launch_bounds__(256)
void ccl_wave2_kernel(const uint32_t* __restrict__ x, int* __restrict__ maxc) {
    __shared__ int Lbuf[IMGS_PER_BLOCK * 512];   // 16 KiB

    const int lane = threadIdx.x & 63;
    const int wv   = threadIdx.x >> 6;
    const int half = lane >> 5;                  // 0: image A, 1: image B
    const int row  = lane & 31;
    const size_t img = (size_t)blockIdx.x * IMGS_PER_BLOCK + wv * 2 + half;
    int* L = Lbuf + (wv * 2 + half) * 512;

    // ---- row-per-lane load: 8 x uint4 = 32 pixels; 1.0f bits >>29 == 1 ----
    const uint4* rp = (const uint4*)(x + img * 1024 + row * 32);
    uint32_t m = 0;
    #pragma unroll
    for (int i = 0; i < 8; ++i) {
        uint4 q = rp[i];
        m |= (q.x >> 29) << (4 * i + 0);
        m |= (q.y >> 29) << (4 * i + 1);
        m |= (q.z >> 29) << (4 * i + 2);
        m |= (q.w >> 29) << (4 * i + 3);
    }

    // foreground count per image (butterfly within 32-lane half)
    int fg = __popc(m);
    #pragma unroll
    for (int off = 1; off < 32; off <<= 1) fg += __shfl_xor(fg, off);

    // ---- run numbering: 64-lane inclusive scan, segmented at lane 32 ----
    uint32_t runStarts = m & ~(m << 1);
    int nruns = __popc(runStarts);
    int scan = nruns;
    #pragma unroll
    for (int off = 1; off < 64; off <<= 1) {
        int u = __shfl_up(scan, off);
        if (lane >= off) scan += u;
    }
    const int totalA   = __shfl(scan, 31);
    const int totalAll = __shfl(scan, 63);
    const int base = scan - nruns - (half ? totalA : 0);
    const int R    = half ? (totalAll - totalA) : totalA;   // runs in my image

    for (int i = row; i < R; i += 32) L[i] = i;

    // ---- edges: one per overlap segment with previous row ----
    uint32_t mprev  = __shfl_up(m, 1);
    uint32_t rsPrev = __shfl_up(runStarts, 1);
    int      bPrev  = __shfl_up(base, 1);
    if (row == 0) mprev = 0;                 // row 0 of each image
    uint32_t ov  = m & mprev;
    uint32_t ovs = ov & ~(ov << 1);

    while (ovs) {
        int c = __ffs(ovs) - 1; ovs &= ovs - 1;
        uint32_t mc = (2u << c) - 1;         // bits 0..c (c=31 -> all ones)
        int a = base  + __popc(runStarts & mc) - 1;
        int b = bPrev + __popc(rsPrev    & mc) - 1;
        int ra = findH(L, a);
        int rb = findH(L, b);
        while (ra != rb) {                   // hook larger root to smaller
            int hi = ra > rb ? ra : rb;
            int lo = ra ^ rb ^ hi;
            int old = atomicCAS(&L[hi], hi, lo);
            if (old == hi) break;            // hooked
            ra = findH(L, old & 511);        // root moved; chase and retry
            rb = lo;
        }
    }

    // ---- fused extract + count: sizes into roots (L[r] = r | size<<9) ----
    // adds are multiples of 512; root ids < 512 so low bits never carry.
    uint32_t mm = m; int k = 0;
    while (mm) {
        int s = __ffs(mm) - 1;
        uint32_t t  = mm + (1u << s);
        uint32_t rm = (t ^ mm) & mm;         // this run's bits
        mm &= ~rm;
        int root = findH(L, base + k);
        atomicAdd(&L[root], __popc(rm) << 9);
        ++k;
    }

    // ---- max component size, per image ----
    int mx = 0;
    for (int i = row; i < R; i += 32) {
        int v = L[i];
        if ((v & 511) == i) mx = max(mx, v >> 9);
    }
    #pragma unroll
    for (int off = 1; off < 32; off <<= 1) mx = max(mx, __shfl_xor(mx, off));

    if (row == 0) maxc[img] = max(mx, 1024 - fg);
}

__global__ __launch_bounds__(64)
void patch_reduce_kernel(const int* __restrict__ maxc, float* __restrict__ out) {
    const int o = blockIdx.x;   // 0..479
    int v = maxc[(size_t)o * 64 + threadIdx.x];
    #pragma unroll
    for (int off = 32; off > 0; off >>= 1)
        v += __shfl_down(v, off);
    if (threadIdx.x == 0) out[o] = (float)(v >> 6);  // integer division by 64
}

extern "C" void kernel_launch(void* const* d_in, const int* in_sizes, int n_in,
                              void* d_out, int out_size, void* d_ws, size_t ws_size,
                              hipStream_t stream) {
    const uint32_t* x = (const uint32_t*)d_in[0];   // float bits; 1.0f>>29 == 1
    float* out = (float*)d_out;
    int* maxc = (int*)d_ws;   // 30720 ints

    ccl_wave2_kernel<<<N_IMGS / IMGS_PER_BLOCK, 256, 0, stream>>>(x, maxc);
    patch_reduce_kernel<<<N_OUT, 64, 0, stream>>>(maxc, out);
}